// Round 1
// baseline (47224.789 us; speedup 1.0000x reference)
//
#include <hip/hip_runtime.h>
#include <math.h>

// Problem constants (fixed by the reference)
#define NB 512      // batch
#define TT 256      // encoder time steps
#define II 128      // encoder input features (== decoder input features OO)
#define HH 1024     // hidden
#define OO 128      // output features
#define TD 128      // forecast steps

// Tiling for the fused LSTM step kernel
#define BM 64       // batch tile
#define BN 16       // hidden-unit tile (each unit has 4 gate rows)
#define KC 32       // K chunk staged in LDS
#define PAD 4       // LDS row padding (floats) to break 128B-stride bank conflicts

__device__ __forceinline__ float sig_(float x) { return 1.0f / (1.0f + expf(-x)); }

// One LSTM cell step: gates = x @ Wih^T + h @ Whh^T + bih + bhh ; update c, h.
// Grid: (NB/BM, HH/BN) = (8, 64) = 512 blocks, 256 threads.
// Each thread computes 2 batch rows x 2 units x 4 gates = 16 accumulators.
__global__ __launch_bounds__(256)
void lstm_step_f32(const float* __restrict__ xbase, long long xstride,
                   const float* __restrict__ Wih,   // [4H, II] row-major
                   const float* __restrict__ Whh,   // [4H, HH] row-major
                   const float* __restrict__ bih,
                   const float* __restrict__ bhh,
                   const float* __restrict__ hin,   // [NB, HH]
                   float* __restrict__ hout,        // [NB, HH]
                   float* __restrict__ cst)         // [NB, HH] (in-place ok: own tile only)
{
    __shared__ float a_lds[BM][KC + PAD];   // input tile (x or h): 64 x 32 (+pad)
    __shared__ float w_lds[64][KC + PAD];   // 4 gates * 16 units rows

    const int tid = threadIdx.x;
    const int bBase = blockIdx.x * BM;
    const int jBase = blockIdx.y * BN;

    const int tj = tid & 7;      // 0..7  -> unit pair
    const int tb = tid >> 3;     // 0..31 -> batch pair

    float acc[2][2][4];          // [b][j][gate]
    #pragma unroll
    for (int ib = 0; ib < 2; ++ib)
        #pragma unroll
        for (int jj = 0; jj < 2; ++jj)
            #pragma unroll
            for (int g = 0; g < 4; ++g) acc[ib][jj][g] = 0.0f;

    const int lrow0 = tid >> 3;        // 0..31 (two passes cover 64 rows)
    const int lcol  = (tid & 7) * 4;   // float4 column

    const int NCH = (II + HH) / KC;    // 4 + 32 = 36 chunks
    for (int ch = 0; ch < NCH; ++ch) {
        const float* abase; long long astr; const float* wbase; int wlen; int k0;
        if (ch < II / KC) {
            abase = xbase; astr = xstride; wbase = Wih; wlen = II; k0 = ch * KC;
        } else {
            abase = hin; astr = HH; wbase = Whh; wlen = HH; k0 = (ch - II / KC) * KC;
        }
        __syncthreads();   // WAR guard on LDS reuse
        #pragma unroll
        for (int r = 0; r < 2; ++r) {
            const int row = lrow0 + r * 32;
            // input tile row
            *(float4*)&a_lds[row][lcol] =
                *(const float4*)&abase[(long long)(bBase + row) * astr + k0 + lcol];
            // weight tile row: row = g*16 + j
            const int g = row >> 4, j = row & 15;
            *(float4*)&w_lds[row][lcol] =
                *(const float4*)&wbase[(long long)(g * HH + jBase + j) * wlen + k0 + lcol];
        }
        __syncthreads();

        #pragma unroll
        for (int kk = 0; kk < KC; kk += 4) {
            float4 av0 = *(const float4*)&a_lds[tb * 2 + 0][kk];
            float4 av1 = *(const float4*)&a_lds[tb * 2 + 1][kk];
            #pragma unroll
            for (int jj = 0; jj < 2; ++jj) {
                #pragma unroll
                for (int g = 0; g < 4; ++g) {
                    const float4 wv = *(const float4*)&w_lds[g * 16 + tj * 2 + jj][kk];
                    acc[0][jj][g] += av0.x * wv.x + av0.y * wv.y + av0.z * wv.z + av0.w * wv.w;
                    acc[1][jj][g] += av1.x * wv.x + av1.y * wv.y + av1.z * wv.z + av1.w * wv.w;
                }
            }
        }
    }

    // Epilogue: activations + state update (PyTorch gate order i,f,g,o)
    #pragma unroll
    for (int ib = 0; ib < 2; ++ib) {
        const int b = bBase + tb * 2 + ib;
        #pragma unroll
        for (int jj = 0; jj < 2; ++jj) {
            const int j = jBase + tj * 2 + jj;
            const float gi = acc[ib][jj][0] + bih[0 * HH + j] + bhh[0 * HH + j];
            const float gf = acc[ib][jj][1] + bih[1 * HH + j] + bhh[1 * HH + j];
            const float gg = acc[ib][jj][2] + bih[2 * HH + j] + bhh[2 * HH + j];
            const float go = acc[ib][jj][3] + bih[3 * HH + j] + bhh[3 * HH + j];
            const float i_ = sig_(gi);
            const float f_ = sig_(gf);
            const float g_ = tanhf(gg);
            const float o_ = sig_(go);
            const long long idx = (long long)b * HH + j;
            const float cn = f_ * cst[idx] + i_ * g_;
            cst[idx] = cn;
            hout[idx] = o_ * tanhf(cn);
        }
    }
}

// y = h @ fc_w^T + fc_b ; writes output slice AND next decoder input.
// Grid: NB blocks (one per batch row), 512 threads = 128 outputs x 4 K-slices.
__global__ __launch_bounds__(512)
void fc_step_f32(const float* __restrict__ h,     // [NB, HH]
                 const float* __restrict__ fcw,   // [OO, HH]
                 const float* __restrict__ fcb,   // [OO]
                 float* __restrict__ outp,        // d_out + t*OO (batch stride TD*OO)
                 float* __restrict__ xbuf)        // [NB, OO]
{
    __shared__ float part[4][OO];
    const int tid = threadIdx.x;
    const int o  = tid & 127;
    const int ks = tid >> 7;    // 0..3
    const int b  = blockIdx.x;

    const float* hr = h + (long long)b * HH + ks * 256;
    const float* wr = fcw + (long long)o * HH + ks * 256;
    float s0 = 0.f, s1 = 0.f;
    #pragma unroll 4
    for (int k = 0; k < 256; k += 8) {
        const float4 hv0 = *(const float4*)&hr[k];
        const float4 wv0 = *(const float4*)&wr[k];
        const float4 hv1 = *(const float4*)&hr[k + 4];
        const float4 wv1 = *(const float4*)&wr[k + 4];
        s0 += hv0.x * wv0.x + hv0.y * wv0.y + hv0.z * wv0.z + hv0.w * wv0.w;
        s1 += hv1.x * wv1.x + hv1.y * wv1.y + hv1.z * wv1.z + hv1.w * wv1.w;
    }
    part[ks][o] = s0 + s1;
    __syncthreads();
    if (tid < OO) {
        const float y = part[0][tid] + part[1][tid] + part[2][tid] + part[3][tid] + fcb[tid];
        outp[(long long)b * (TD * OO) + tid] = y;
        xbuf[(long long)b * OO + tid] = y;
    }
}

extern "C" void kernel_launch(void* const* d_in, const int* in_sizes, int n_in,
                              void* d_out, int out_size, void* d_ws, size_t ws_size,
                              hipStream_t stream) {
    const float* enc   = (const float*)d_in[0];
    const float* Wih_e = (const float*)d_in[1];
    const float* Whh_e = (const float*)d_in[2];
    const float* bih_e = (const float*)d_in[3];
    const float* bhh_e = (const float*)d_in[4];
    const float* Wih_d = (const float*)d_in[5];
    const float* Whh_d = (const float*)d_in[6];
    const float* bih_d = (const float*)d_in[7];
    const float* bhh_d = (const float*)d_in[8];
    const float* fcw   = (const float*)d_in[9];
    const float* fcb   = (const float*)d_in[10];
    float* out = (float*)d_out;

    // Workspace: h ping-pong, c, decoder input buffer
    float* h0 = (float*)d_ws;
    float* h1 = h0 + (size_t)NB * HH;
    float* c  = h1 + (size_t)NB * HH;
    float* xb = c  + (size_t)NB * HH;
    const size_t zbytes = ((size_t)3 * NB * HH + (size_t)NB * OO) * sizeof(float);
    hipMemsetAsync(d_ws, 0, zbytes, stream);   // h0 = c = xb = 0

    const dim3 grid(NB / BM, HH / BN);  // (8, 64)

    const float* hin = h0;
    float* houtp = h1;
    for (int t = 0; t < TT; ++t) {
        lstm_step_f32<<<grid, 256, 0, stream>>>(
            enc + (size_t)t * II, (long long)TT * II,
            Wih_e, Whh_e, bih_e, bhh_e, hin, houtp, c);
        float* tmp = (float*)hin; hin = houtp; houtp = tmp;
    }
    for (int t = 0; t < TD; ++t) {
        lstm_step_f32<<<grid, 256, 0, stream>>>(
            xb, (long long)OO,
            Wih_d, Whh_d, bih_d, bhh_d, hin, houtp, c);
        fc_step_f32<<<NB, 512, 0, stream>>>(
            houtp, fcw, fcb, out + (size_t)t * OO, xb);
        float* tmp = (float*)hin; hin = houtp; houtp = tmp;
    }
}

// Round 2
// 18324.033 us; speedup vs baseline: 2.5772x; 2.5772x over previous
//
#include <hip/hip_runtime.h>
#include <math.h>

#define NB 512
#define TT 256
#define II 128
#define HH 1024
#define OO 128
#define TD 128
#define KC 32
#define NCH 36          // (II+HH)/KC
#define KW (II + HH)    // 1152, W' row length

typedef __attribute__((ext_vector_type(8))) short bf16x8;
typedef __attribute__((ext_vector_type(4))) float f32x4;

__device__ __forceinline__ unsigned short f2bf(float x) {
    union { float f; unsigned u; } un; un.f = x;
    unsigned r = un.u + 0x7fffu + ((un.u >> 16) & 1u);  // RN-even
    return (unsigned short)(r >> 16);
}
__device__ __forceinline__ float bf2f(unsigned short h) {
    union { unsigned u; float f; } un; un.u = ((unsigned)h) << 16; return un.f;
}
__device__ __forceinline__ float sig_(float x) { return 1.0f / (1.0f + expf(-x)); }

__device__ __forceinline__ void gl_lds16(const void* g, void* l) {
    __builtin_amdgcn_global_load_lds(
        (const __attribute__((address_space(1))) unsigned int*)g,
        (__attribute__((address_space(3))) unsigned int*)l, 16, 0, 0);
}

// One LSTM step. gates[b][n'] = sum_k A[b][k] * W'[n'][k], n' = j*4 + g (gate-interleaved).
// A = [x (fp32, reg-staged+split) | h (bf16 hi/lo)] over K=1152.
// Grid 256 blocks (XCD-chunked decode), 256 threads (4 waves), block tile 64x128,
// wave tile 64x32, KC=32 double-buffered, hi/lo interleaved 16B slots, XOR-swizzled.
__global__ __launch_bounds__(256)
void lstm_step_mfma(const float* __restrict__ x, long long xstride,
                    const unsigned short* __restrict__ Whi,
                    const unsigned short* __restrict__ Wlo,
                    const float* __restrict__ bsum,
                    const unsigned short* __restrict__ Hhi_in,
                    const unsigned short* __restrict__ Hlo_in,
                    unsigned short* __restrict__ Hhi_out,
                    unsigned short* __restrict__ Hlo_out,
                    float* __restrict__ h32, int write_h32,
                    float* __restrict__ cst)
{
    __shared__ __align__(16) unsigned char smem[49152];  // 2 x 24KB buffers; epilogue reuses

    const int tid = threadIdx.x;
    // XCD-chunked mapping: hw id%8 = XCD; XCD k owns n-groups y = 4k..4k+3 (W slice L2-resident)
    const int id  = blockIdx.x;
    const int xcd = id & 7;
    const int mm  = id >> 3;               // 0..31
    const int bBase = (mm & 7) * 64;       // batch tile base
    const int nBase = (xcd * 4 + (mm >> 3)) * 128;  // n' tile base

    const int l  = tid & 63;
    const int w  = tid >> 6;               // wave 0..3
    const int lr = l & 15;
    const int lg = l >> 4;                 // 0..3 -> k-octet
    const int sw = lr & 7;                 // frag-row & 7 (same for all mi/ni)

    // ds_read offsets (relative to buffer base). Layout: A [64 rows][128B], B at +8192 [128 rows][128B].
    // Row = 8 slots x 16B; slot 2u = hi octet u, 2u+1 = lo octet u; stored slot = logical ^ (row&7).
    int a_hi_off[4], a_lo_off[4], b_hi_off[2], b_lo_off[2];
    #pragma unroll
    for (int mi = 0; mi < 4; ++mi) {
        const int row = mi * 16 + lr;
        a_hi_off[mi] = row * 128 + ((lg * 2) ^ sw) * 16;
        a_lo_off[mi] = row * 128 + ((lg * 2 + 1) ^ sw) * 16;
    }
    #pragma unroll
    for (int ni = 0; ni < 2; ++ni) {
        const int row = w * 32 + ni * 16 + lr;
        b_hi_off[ni] = 8192 + row * 128 + ((lg * 2) ^ sw) * 16;
        b_lo_off[ni] = 8192 + row * 128 + ((lg * 2 + 1) ^ sw) * 16;
    }

    // staging constants: each global_load_lds writes 1KB = 8 rows x 128B linearly;
    // lane l -> row +(l>>3), slot (l&7); source slot pre-swizzled: sg = (l&7)^(l>>3)
    const int srow = l >> 3;
    const int sg   = (l & 7) ^ srow;
    const int ssel = sg & 1;       // 0 = hi array, 1 = lo array
    const int soct = sg >> 1;      // source k-octet

    f32x4 acc[4][2];
    #pragma unroll
    for (int mi = 0; mi < 4; ++mi)
        #pragma unroll
        for (int ni = 0; ni < 2; ++ni)
            acc[mi][ni] = (f32x4){0.f, 0.f, 0.f, 0.f};

    auto stage = [&](int cc, int buf) {
        const unsigned bufb = (unsigned)buf * 24576u;
        const int k0 = cc * KC;
        if (k0 >= II) {
            // A from h state (bf16 hi/lo), async direct-to-LDS
            const int kh = k0 - II;
            #pragma unroll
            for (int i = 0; i < 2; ++i) {
                const int p = w * 2 + i;                 // A part 0..7
                const int row = p * 8 + srow;
                const unsigned short* base = ssel ? Hlo_in : Hhi_in;
                gl_lds16(base + (size_t)(bBase + row) * HH + kh + soct * 8,
                         &smem[bufb + p * 1024]);
            }
        } else {
            // A from fp32 x: reg-stage, split to hi/lo, swizzled ds_write
            const int row = tid >> 2;                    // 0..63
            const int h4 = tid & 3;                      // k-octet pair
            const float* s = x + (size_t)(bBase + row) * xstride + k0 + h4 * 8;
            const float4 v0 = *(const float4*)s;
            const float4 v1 = *(const float4*)(s + 4);
            const float vv[8] = {v0.x, v0.y, v0.z, v0.w, v1.x, v1.y, v1.z, v1.w};
            bf16x8 hv, lv;
            #pragma unroll
            for (int i2 = 0; i2 < 8; ++i2) {
                const unsigned short h = f2bf(vv[i2]);
                hv[i2] = (short)h;
                lv[i2] = (short)f2bf(vv[i2] - bf2f(h));
            }
            const int rsw = row & 7;
            *(bf16x8*)&smem[bufb + row * 128 + ((2 * h4) ^ rsw) * 16] = hv;
            *(bf16x8*)&smem[bufb + row * 128 + ((2 * h4 + 1) ^ rsw) * 16] = lv;
        }
        // B from W' (bf16 hi/lo), always async
        #pragma unroll
        for (int i = 0; i < 4; ++i) {
            const int q = w * 4 + i;                     // B part 0..15
            const int row = q * 8 + srow;
            const unsigned short* base = ssel ? Wlo : Whi;
            gl_lds16(base + (size_t)(nBase + row) * KW + k0 + soct * 8,
                     &smem[bufb + 8192 + q * 1024]);
        }
    };

    auto compute = [&](int buf) {
        const unsigned bufb = (unsigned)buf * 24576u;
        bf16x8 ah[4], al[4], bh[2], bl[2];
        #pragma unroll
        for (int mi = 0; mi < 4; ++mi) {
            ah[mi] = *(const bf16x8*)&smem[bufb + a_hi_off[mi]];
            al[mi] = *(const bf16x8*)&smem[bufb + a_lo_off[mi]];
        }
        #pragma unroll
        for (int ni = 0; ni < 2; ++ni) {
            bh[ni] = *(const bf16x8*)&smem[bufb + b_hi_off[ni]];
            bl[ni] = *(const bf16x8*)&smem[bufb + b_lo_off[ni]];
        }
        #pragma unroll
        for (int mi = 0; mi < 4; ++mi)
            #pragma unroll
            for (int ni = 0; ni < 2; ++ni) {
                acc[mi][ni] = __builtin_amdgcn_mfma_f32_16x16x32_bf16(ah[mi], bh[ni], acc[mi][ni], 0, 0, 0);
                acc[mi][ni] = __builtin_amdgcn_mfma_f32_16x16x32_bf16(ah[mi], bl[ni], acc[mi][ni], 0, 0, 0);
                acc[mi][ni] = __builtin_amdgcn_mfma_f32_16x16x32_bf16(al[mi], bh[ni], acc[mi][ni], 0, 0, 0);
            }
    };

    stage(0, 0);
    __syncthreads();
    for (int c = 0; c < NCH; ++c) {
        if (c + 1 < NCH) stage(c + 1, (c + 1) & 1);   // issue next-buffer loads BEFORE compute
        compute(c & 1);
        __syncthreads();                               // drains vmcnt+lgkmcnt, buffers swap
    }

    // ---- epilogue: gates -> LDS (f32, +bias), then per-unit float4 read ----
    float* glds = (float*)smem;                        // [64][140] f32, 35840B
    #pragma unroll
    for (int ni = 0; ni < 2; ++ni) {
        const int col = w * 32 + ni * 16 + lr;         // local n'
        const float bv = bsum[nBase + col];
        #pragma unroll
        for (int mi = 0; mi < 4; ++mi)
            #pragma unroll
            for (int r = 0; r < 4; ++r)
                glds[(mi * 16 + lg * 4 + r) * 140 + col] = acc[mi][ni][r] + bv;
    }
    __syncthreads();

    const int jl = tid & 31;                           // local unit
    const int b0 = tid >> 5;                           // 0..7
    const int jglob = (nBase >> 2) + jl;
    #pragma unroll
    for (int ii = 0; ii < 8; ++ii) {
        const int bl_ = ii * 8 + b0;
        const float4 g4 = *(const float4*)&glds[bl_ * 140 + jl * 4];  // i,f,g,o
        const size_t idx = (size_t)(bBase + bl_) * HH + jglob;
        const float i_ = sig_(g4.x);
        const float f_ = sig_(g4.y);
        const float gg = tanhf(g4.z);
        const float o_ = sig_(g4.w);
        const float cn = f_ * cst[idx] + i_ * gg;
        cst[idx] = cn;
        const float hn = o_ * tanhf(cn);
        const unsigned short hh = f2bf(hn);
        Hhi_out[idx] = hh;
        Hlo_out[idx] = f2bf(hn - bf2f(hh));
        if (write_h32) h32[idx] = hn;
    }
}

// W reorder+split: W'[n'][k], n' = j*4+g, k = [Wih | Whh]; also bsum = bih+bhh in n' order.
__global__ __launch_bounds__(128)
void convert_w(const float* __restrict__ Wih, const float* __restrict__ Whh,
               const float* __restrict__ bih, const float* __restrict__ bhh,
               unsigned short* __restrict__ Whi, unsigned short* __restrict__ Wlo,
               float* __restrict__ bsum)
{
    const int np = blockIdx.x;          // n'
    const int g = np & 3, j = np >> 2;
    const int n = g * HH + j;
    for (int k = threadIdx.x; k < KW; k += 128) {
        const float v = (k < II) ? Wih[(size_t)n * II + k] : Whh[(size_t)n * HH + (k - II)];
        const unsigned short h = f2bf(v);
        Whi[(size_t)np * KW + k] = h;
        Wlo[(size_t)np * KW + k] = f2bf(v - bf2f(h));
    }
    if (threadIdx.x == 0) bsum[np] = bih[n] + bhh[n];
}

// y = h @ fc_w^T + fc_b ; writes output slice AND next decoder input (fp32).
__global__ __launch_bounds__(512)
void fc_step_f32(const float* __restrict__ h, const float* __restrict__ fcw,
                 const float* __restrict__ fcb, float* __restrict__ outp,
                 float* __restrict__ xbuf)
{
    __shared__ float part[4][OO];
    const int tid = threadIdx.x;
    const int o  = tid & 127;
    const int ks = tid >> 7;
    const int b  = blockIdx.x;
    const float* hr = h + (size_t)b * HH + ks * 256;
    const float* wr = fcw + (size_t)o * HH + ks * 256;
    float s0 = 0.f, s1 = 0.f;
    #pragma unroll 4
    for (int k = 0; k < 256; k += 8) {
        const float4 hv0 = *(const float4*)&hr[k];
        const float4 wv0 = *(const float4*)&wr[k];
        const float4 hv1 = *(const float4*)&hr[k + 4];
        const float4 wv1 = *(const float4*)&wr[k + 4];
        s0 += hv0.x * wv0.x + hv0.y * wv0.y + hv0.z * wv0.z + hv0.w * wv0.w;
        s1 += hv1.x * wv1.x + hv1.y * wv1.y + hv1.z * wv1.z + hv1.w * wv1.w;
    }
    part[ks][o] = s0 + s1;
    __syncthreads();
    if (tid < OO) {
        const float y = part[0][tid] + part[1][tid] + part[2][tid] + part[3][tid] + fcb[tid];
        outp[(size_t)b * (TD * OO) + tid] = y;
        xbuf[(size_t)b * OO + tid] = y;
    }
}

extern "C" void kernel_launch(void* const* d_in, const int* in_sizes, int n_in,
                              void* d_out, int out_size, void* d_ws, size_t ws_size,
                              hipStream_t stream) {
    const float* enc   = (const float*)d_in[0];
    const float* Wih_e = (const float*)d_in[1];
    const float* Whh_e = (const float*)d_in[2];
    const float* bih_e = (const float*)d_in[3];
    const float* bhh_e = (const float*)d_in[4];
    const float* Wih_d = (const float*)d_in[5];
    const float* Whh_d = (const float*)d_in[6];
    const float* bih_d = (const float*)d_in[7];
    const float* bhh_d = (const float*)d_in[8];
    const float* fcw   = (const float*)d_in[9];
    const float* fcb   = (const float*)d_in[10];
    float* out = (float*)d_out;

    // Workspace layout (all sizes 256B-aligned). Zero region first: [c][Hhi0][Hlo0][xb]
    char* p = (char*)d_ws;
    float* c            = (float*)p;            p += (size_t)NB * HH * 4;   // 2MB
    unsigned short* Hhi0 = (unsigned short*)p;  p += (size_t)NB * HH * 2;   // 1MB
    unsigned short* Hlo0 = (unsigned short*)p;  p += (size_t)NB * HH * 2;
    float* xb           = (float*)p;            p += (size_t)NB * OO * 4;   // 256KB
    const size_t zbytes = (size_t)(p - (char*)d_ws);
    float* h32          = (float*)p;            p += (size_t)NB * HH * 4;
    unsigned short* Hhi1 = (unsigned short*)p;  p += (size_t)NB * HH * 2;
    unsigned short* Hlo1 = (unsigned short*)p;  p += (size_t)NB * HH * 2;
    unsigned short* Whi_e = (unsigned short*)p; p += (size_t)4 * HH * KW * 2;
    unsigned short* Wlo_e = (unsigned short*)p; p += (size_t)4 * HH * KW * 2;
    unsigned short* Whi_d = (unsigned short*)p; p += (size_t)4 * HH * KW * 2;
    unsigned short* Wlo_d = (unsigned short*)p; p += (size_t)4 * HH * KW * 2;
    float* bsum_e       = (float*)p;            p += (size_t)4 * HH * 4;
    float* bsum_d       = (float*)p;            p += (size_t)4 * HH * 4;

    convert_w<<<4 * HH, 128, 0, stream>>>(Wih_e, Whh_e, bih_e, bhh_e, Whi_e, Wlo_e, bsum_e);
    convert_w<<<4 * HH, 128, 0, stream>>>(Wih_d, Whh_d, bih_d, bhh_d, Whi_d, Wlo_d, bsum_d);
    hipMemsetAsync(d_ws, 0, zbytes, stream);

    const unsigned short *hi_in = Hhi0, *lo_in = Hlo0;
    unsigned short *hi_out = Hhi1, *lo_out = Hlo1;

    for (int t = 0; t < TT; ++t) {
        lstm_step_mfma<<<256, 256, 0, stream>>>(
            enc + (size_t)t * II, (long long)TT * II,
            Whi_e, Wlo_e, bsum_e, hi_in, lo_in, hi_out, lo_out, h32, 0, c);
        const unsigned short* th = hi_in; hi_in = hi_out; hi_out = (unsigned short*)th;
        const unsigned short* tl = lo_in; lo_in = lo_out; lo_out = (unsigned short*)tl;
    }
    for (int t = 0; t < TD; ++t) {
        lstm_step_mfma<<<256, 256, 0, stream>>>(
            xb, (long long)OO,
            Whi_d, Wlo_d, bsum_d, hi_in, lo_in, hi_out, lo_out, h32, 1, c);
        fc_step_f32<<<NB, 512, 0, stream>>>(h32, fcw, fcb, out + (size_t)t * OO, xb);
        const unsigned short* th = hi_in; hi_in = hi_out; hi_out = (unsigned short*)th;
        const unsigned short* tl = lo_in; lo_in = lo_out; lo_out = (unsigned short*)tl;
    }
}

// Round 4
// 14714.221 us; speedup vs baseline: 3.2095x; 1.2453x over previous
//
#include <hip/hip_runtime.h>
#include <math.h>

#define NB 512
#define TT 256
#define II 128
#define HH 1024
#define OO 128
#define TD 128
#define KC 64
#define NCHV 18         // (II+HH)/KC
#define KW (II + HH)    // 1152

typedef __attribute__((ext_vector_type(8))) short bf16x8;
typedef __attribute__((ext_vector_type(4))) float f32x4;

__device__ __forceinline__ unsigned short f2bf(float x) {
    union { float f; unsigned u; } un; un.f = x;
    unsigned r = un.u + 0x7fffu + ((un.u >> 16) & 1u);  // RN-even
    return (unsigned short)(r >> 16);
}
__device__ __forceinline__ float bf2f(unsigned short h) {
    union { unsigned u; float f; } un; un.u = ((unsigned)h) << 16; return un.f;
}
__device__ __forceinline__ float sig_(float x) { return 1.0f / (1.0f + expf(-x)); }

__device__ __forceinline__ void gl_lds16(const void* g, void* l) {
    __builtin_amdgcn_global_load_lds(
        (const __attribute__((address_space(1))) unsigned int*)g,
        (__attribute__((address_space(3))) unsigned int*)l, 16, 0, 0);
}

// One LSTM step. gates[b][n'] = sum_k A[b][k] * W'[n'][k], n' = j*4+g (gate-interleaved).
// A = [x (fp32, reg-split) | h (bf16 hi/lo)], K = 1152, 3-term hi/lo MFMA (hh, hl, lh).
// Grid 512 blocks (8 batch x 64 n-tiles, XCD-chunked), 256 thr (4 waves, 2x2 wave grid),
// block tile 64x64, wave tile 32x32, KC=64 double-buffered (2x32KB LDS), 2 blocks/CU.
// LDS row = 256B = 16 slots x 16B; slot 2u=hi octet u, 2u+1=lo octet u (u=0..7);
// stored slot = logical ^ (row & 15)  -> conflict-free ds_read_b128.
__global__ __launch_bounds__(256, 2)
void lstm_step_mfma(const float* __restrict__ x, long long xstride,
                    const unsigned short* __restrict__ Whi,
                    const unsigned short* __restrict__ Wlo,
                    const float* __restrict__ bsum,
                    const unsigned short* __restrict__ Hhi_in,
                    const unsigned short* __restrict__ Hlo_in,
                    unsigned short* __restrict__ Hhi_out,
                    unsigned short* __restrict__ Hlo_out,
                    float* __restrict__ h32, int write_h32,
                    float* __restrict__ cst)
{
    __shared__ __align__(16) unsigned char smem[65536];

    const int tid = threadIdx.x;
    const int id  = blockIdx.x;
    const int xcd = id & 7;                 // hw round-robin -> XCD
    const int nb  = (id >> 3) & 7;
    const int bb  = id >> 6;
    const int bBase = bb * 64;
    const int nBase = (xcd * 8 + nb) * 64;  // XCD's W slice (8 n-tiles) stays L2-resident

    const int l  = tid & 63;
    const int w  = tid >> 6;                // wave 0..3
    const int wm = w & 1, wn = w >> 1;      // 2x2 wave grid
    const int lr = l & 15;
    const int lg = l >> 4;                  // k-octet within 32-k subtile

    // ds_read byte offsets: [mi][ks][hi/lo]
    int a_off[2][2][2], b_off[2][2][2];
    #pragma unroll
    for (int mi = 0; mi < 2; ++mi)
        #pragma unroll
        for (int ks = 0; ks < 2; ++ks)
            #pragma unroll
            for (int h = 0; h < 2; ++h) {
                const int arow = wm * 32 + mi * 16 + lr;
                const int brow = wn * 32 + mi * 16 + lr;   // mi doubles as ni
                const int ls = 2 * (ks * 4 + lg) + h;
                a_off[mi][ks][h] = arow * 256 + ((ls ^ (arow & 15)) * 16);
                b_off[mi][ks][h] = 16384 + brow * 256 + ((ls ^ (brow & 15)) * 16);
            }

    // gl_lds16 source decode: instr p writes 1KB = 4 rows x 256B; lane l -> row p*4+(l>>4),
    // stored slot l&15; logical slot = (l&15) ^ (row&15)
    const int srow4 = l >> 4;
    const int sslot = l & 15;

    f32x4 acc[2][2];
    #pragma unroll
    for (int mi = 0; mi < 2; ++mi)
        #pragma unroll
        for (int ni = 0; ni < 2; ++ni)
            acc[mi][ni] = (f32x4){0.f, 0.f, 0.f, 0.f};

    auto stage = [&](int cc, int buf) {
        const unsigned bufb = (unsigned)buf * 32768u;
        const int k0 = cc * KC;
        // B from W' (always async direct-to-LDS)
        #pragma unroll
        for (int i = 0; i < 4; ++i) {
            const int p = w * 4 + i;
            const int r = p * 4 + srow4;
            const int ls = sslot ^ (r & 15);
            const unsigned short* base = (ls & 1) ? Wlo : Whi;
            gl_lds16(base + (size_t)(nBase + r) * KW + k0 + (ls >> 1) * 8,
                     &smem[bufb + 16384u + (unsigned)p * 1024u]);
        }
        if (k0 >= II) {
            // A from h state (bf16 hi/lo)
            const int kh = k0 - II;
            #pragma unroll
            for (int i = 0; i < 4; ++i) {
                const int p = w * 4 + i;
                const int r = p * 4 + srow4;
                const int ls = sslot ^ (r & 15);
                const unsigned short* base = (ls & 1) ? Hlo_in : Hhi_in;
                gl_lds16(base + (size_t)(bBase + r) * HH + kh + (ls >> 1) * 8,
                         &smem[bufb + (unsigned)p * 1024u]);
            }
        } else {
            // A from fp32 x: reg-stage 16 floats/thread, split hi/lo, swizzled ds_write
            const int row = tid >> 2, q = tid & 3;
            const float* s = x + (size_t)(bBase + row) * xstride + k0 + q * 16;
            const float4 va = *(const float4*)s;
            const float4 vb = *(const float4*)(s + 4);
            const float4 vc = *(const float4*)(s + 8);
            const float4 vd = *(const float4*)(s + 12);
            const float vv[16] = {va.x, va.y, va.z, va.w, vb.x, vb.y, vb.z, vb.w,
                                  vc.x, vc.y, vc.z, vc.w, vd.x, vd.y, vd.z, vd.w};
            const int rs = row & 15;
            #pragma unroll
            for (int j = 0; j < 2; ++j) {
                bf16x8 hv, lv;
                #pragma unroll
                for (int e = 0; e < 8; ++e) {
                    const float val = vv[j * 8 + e];
                    const unsigned short hb = f2bf(val);
                    hv[e] = (short)hb;
                    lv[e] = (short)f2bf(val - bf2f(hb));
                }
                *(bf16x8*)&smem[bufb + row * 256 + (unsigned)(((4 * q + 2 * j) ^ rs) * 16)] = hv;
                *(bf16x8*)&smem[bufb + row * 256 + (unsigned)(((4 * q + 2 * j + 1) ^ rs) * 16)] = lv;
            }
        }
    };

    auto compute = [&](int buf) {
        const unsigned bufb = (unsigned)buf * 32768u;
        #pragma unroll
        for (int ks = 0; ks < 2; ++ks) {
            bf16x8 ah[2], al[2], bh[2], bl[2];
            #pragma unroll
            for (int mi = 0; mi < 2; ++mi) {
                ah[mi] = *(const bf16x8*)&smem[bufb + a_off[mi][ks][0]];
                al[mi] = *(const bf16x8*)&smem[bufb + a_off[mi][ks][1]];
            }
            #pragma unroll
            for (int ni = 0; ni < 2; ++ni) {
                bh[ni] = *(const bf16x8*)&smem[bufb + b_off[ni][ks][0]];
                bl[ni] = *(const bf16x8*)&smem[bufb + b_off[ni][ks][1]];
            }
            #pragma unroll
            for (int mi = 0; mi < 2; ++mi)
                #pragma unroll
                for (int ni = 0; ni < 2; ++ni) {
                    acc[mi][ni] = __builtin_amdgcn_mfma_f32_16x16x32_bf16(ah[mi], bh[ni], acc[mi][ni], 0, 0, 0);
                    acc[mi][ni] = __builtin_amdgcn_mfma_f32_16x16x32_bf16(ah[mi], bl[ni], acc[mi][ni], 0, 0, 0);
                    acc[mi][ni] = __builtin_amdgcn_mfma_f32_16x16x32_bf16(al[mi], bh[ni], acc[mi][ni], 0, 0, 0);
                }
        }
    };

    stage(0, 0);
    __syncthreads();
    #pragma unroll 1
    for (int c = 0; c < NCHV; ++c) {
        if (c + 1 < NCHV) stage(c + 1, (c + 1) & 1);  // prefetch before compute
        compute(c & 1);
        __syncthreads();
    }

    // ---- epilogue: gates -> LDS (f32, +bias), then per-unit float4 read ----
    float* glds = (float*)smem;                       // [64][68] = 17408B (buffer 0, safe)
    #pragma unroll
    for (int ni = 0; ni < 2; ++ni) {
        const int col = wn * 32 + ni * 16 + lr;
        const float bv = bsum[nBase + col];
        #pragma unroll
        for (int mi = 0; mi < 2; ++mi)
            #pragma unroll
            for (int r = 0; r < 4; ++r)
                glds[(wm * 32 + mi * 16 + lg * 4 + r) * 68 + col] = acc[mi][ni][r] + bv;
    }
    __syncthreads();

    const int ju = tid & 15;                          // local unit (16 units per tile)
    const int jglob = (nBase >> 2) + ju;
    #pragma unroll
    for (int ii = 0; ii < 4; ++ii) {
        const int brow = ii * 16 + (tid >> 4);
        const float4 g4 = *(const float4*)&glds[brow * 68 + ju * 4];  // i,f,g,o
        const size_t idx = (size_t)(bBase + brow) * HH + jglob;
        const float i_ = sig_(g4.x);
        const float f_ = sig_(g4.y);
        const float gg = tanhf(g4.z);
        const float o_ = sig_(g4.w);
        const float cn = f_ * cst[idx] + i_ * gg;
        cst[idx] = cn;
        const float hn = o_ * tanhf(cn);
        const unsigned short hh = f2bf(hn);
        Hhi_out[idx] = hh;
        Hlo_out[idx] = f2bf(hn - bf2f(hh));
        if (write_h32) h32[idx] = hn;
    }
}

// W reorder+split: W'[n'][k], n' = j*4+g, k = [Wih | Whh]; bsum = bih+bhh in n' order.
__global__ __launch_bounds__(128)
void convert_w(const float* __restrict__ Wih, const float* __restrict__ Whh,
               const float* __restrict__ bih, const float* __restrict__ bhh,
               unsigned short* __restrict__ Whi, unsigned short* __restrict__ Wlo,
               float* __restrict__ bsum)
{
    const int np = blockIdx.x;
    const int g = np & 3, j = np >> 2;
    const int n = g * HH + j;
    for (int k = threadIdx.x; k < KW; k += 128) {
        const float v = (k < II) ? Wih[(size_t)n * II + k] : Whh[(size_t)n * HH + (k - II)];
        const unsigned short h = f2bf(v);
        Whi[(size_t)np * KW + k] = h;
        Wlo[(size_t)np * KW + k] = f2bf(v - bf2f(h));
    }
    if (threadIdx.x == 0) bsum[np] = bih[n] + bhh[n];
}

// y = h @ fc_w^T + fc_b ; writes output slice AND next decoder input (fp32).
__global__ __launch_bounds__(512)
void fc_step_f32(const float* __restrict__ h, const float* __restrict__ fcw,
                 const float* __restrict__ fcb, float* __restrict__ outp,
                 float* __restrict__ xbuf)
{
    __shared__ float part[4][OO];
    const int tid = threadIdx.x;
    const int o  = tid & 127;
    const int ks = tid >> 7;
    const int b  = blockIdx.x;
    const float* hr = h + (size_t)b * HH + ks * 256;
    const float* wr = fcw + (size_t)o * HH + ks * 256;
    float s0 = 0.f, s1 = 0.f;
    #pragma unroll 4
    for (int k = 0; k < 256; k += 8) {
        const float4 hv0 = *(const float4*)&hr[k];
        const float4 wv0 = *(const float4*)&wr[k];
        const float4 hv1 = *(const float4*)&hr[k + 4];
        const float4 wv1 = *(const float4*)&wr[k + 4];
        s0 += hv0.x * wv0.x + hv0.y * wv0.y + hv0.z * wv0.z + hv0.w * wv0.w;
        s1 += hv1.x * wv1.x + hv1.y * wv1.y + hv1.z * wv1.z + hv1.w * wv1.w;
    }
    part[ks][o] = s0 + s1;
    __syncthreads();
    if (tid < OO) {
        const float y = part[0][tid] + part[1][tid] + part[2][tid] + part[3][tid] + fcb[tid];
        outp[(size_t)b * (TD * OO) + tid] = y;
        xbuf[(size_t)b * OO + tid] = y;
    }
}

extern "C" void kernel_launch(void* const* d_in, const int* in_sizes, int n_in,
                              void* d_out, int out_size, void* d_ws, size_t ws_size,
                              hipStream_t stream) {
    const float* enc   = (const float*)d_in[0];
    const float* Wih_e = (const float*)d_in[1];
    const float* Whh_e = (const float*)d_in[2];
    const float* bih_e = (const float*)d_in[3];
    const float* bhh_e = (const float*)d_in[4];
    const float* Wih_d = (const float*)d_in[5];
    const float* Whh_d = (const float*)d_in[6];
    const float* bih_d = (const float*)d_in[7];
    const float* bhh_d = (const float*)d_in[8];
    const float* fcw   = (const float*)d_in[9];
    const float* fcb   = (const float*)d_in[10];
    float* out = (float*)d_out;

    // Workspace layout. Zero region first: [c][Hhi0][Hlo0][xb]
    char* p = (char*)d_ws;
    float* c            = (float*)p;            p += (size_t)NB * HH * 4;
    unsigned short* Hhi0 = (unsigned short*)p;  p += (size_t)NB * HH * 2;
    unsigned short* Hlo0 = (unsigned short*)p;  p += (size_t)NB * HH * 2;
    float* xb           = (float*)p;            p += (size_t)NB * OO * 4;
    const size_t zbytes = (size_t)(p - (char*)d_ws);
    float* h32          = (float*)p;            p += (size_t)NB * HH * 4;
    unsigned short* Hhi1 = (unsigned short*)p;  p += (size_t)NB * HH * 2;
    unsigned short* Hlo1 = (unsigned short*)p;  p += (size_t)NB * HH * 2;
    unsigned short* Whi_e = (unsigned short*)p; p += (size_t)4 * HH * KW * 2;
    unsigned short* Wlo_e = (unsigned short*)p; p += (size_t)4 * HH * KW * 2;
    unsigned short* Whi_d = (unsigned short*)p; p += (size_t)4 * HH * KW * 2;
    unsigned short* Wlo_d = (unsigned short*)p; p += (size_t)4 * HH * KW * 2;
    float* bsum_e       = (float*)p;            p += (size_t)4 * HH * 4;
    float* bsum_d       = (float*)p;            p += (size_t)4 * HH * 4;

    convert_w<<<4 * HH, 128, 0, stream>>>(Wih_e, Whh_e, bih_e, bhh_e, Whi_e, Wlo_e, bsum_e);
    convert_w<<<4 * HH, 128, 0, stream>>>(Wih_d, Whh_d, bih_d, bhh_d, Whi_d, Wlo_d, bsum_d);
    hipMemsetAsync(d_ws, 0, zbytes, stream);

    const unsigned short *hi_in = Hhi0, *lo_in = Hlo0;
    unsigned short *hi_out = Hhi1, *lo_out = Hlo1;

    for (int t = 0; t < TT; ++t) {
        lstm_step_mfma<<<512, 256, 0, stream>>>(
            enc + (size_t)t * II, (long long)TT * II,
            Whi_e, Wlo_e, bsum_e, hi_in, lo_in, hi_out, lo_out, h32, 0, c);
        const unsigned short* th = hi_in; hi_in = hi_out; hi_out = (unsigned short*)th;
        const unsigned short* tl = lo_in; lo_in = lo_out; lo_out = (unsigned short*)tl;
    }
    for (int t = 0; t < TD; ++t) {
        lstm_step_mfma<<<512, 256, 0, stream>>>(
            xb, (long long)OO,
            Whi_d, Wlo_d, bsum_d, hi_in, lo_in, hi_out, lo_out, h32, 1, c);
        fc_step_f32<<<NB, 512, 0, stream>>>(h32, fcw, fcb, out + (size_t)t * OO, xb);
        const unsigned short* th = hi_in; hi_in = hi_out; hi_out = (unsigned short*)th;
        const unsigned short* tl = lo_in; lo_in = lo_out; lo_out = (unsigned short*)tl;
    }
}